// Round 15
// baseline (83.167 us; speedup 1.0000x reference)
//
#include <hip/hip_runtime.h>
#include <hip/hip_bf16.h>
#include <stdint.h>

// ---------------------------------------------------------------------------
// EfficientSelfAttention (PVT SRA): B=4, N=4096, C=256, HEADS=8, hd=32, SR=2
// Pipeline: prep (cast x + im2col + LDS-tiled weight transpose) |
//           GEMM(Q)+GEMM(conv,split-K x2) fused | LN(sum 2 partials) |
//           GEMM(KV -> frag-major K,V) |
//           flash-attn (frag streams, kv-split x2, ones-MFMA lsum,
//                       2-stage score pipeline) | GEMM(proj)
// ---------------------------------------------------------------------------

typedef __attribute__((ext_vector_type(8))) short short8;
typedef __attribute__((ext_vector_type(4))) short short4v;
typedef __attribute__((ext_vector_type(2))) float f32x2;
typedef __attribute__((ext_vector_type(2))) unsigned int u32x2;
typedef __attribute__((ext_vector_type(4))) float f32x4;
typedef __attribute__((ext_vector_type(16))) float f32x16;

#define AS1 __attribute__((address_space(1)))
#define AS3 __attribute__((address_space(3)))

static __device__ __forceinline__ unsigned short f2bfu(float f) {
  __hip_bfloat16 h = __float2bfloat16(f);
  unsigned short u; __builtin_memcpy(&u, &h, 2); return u;
}

static __device__ __forceinline__ float fast_exp2(float x) {
#if __has_builtin(__builtin_amdgcn_exp2f)
  return __builtin_amdgcn_exp2f(x);
#else
  return __expf(x * 0.6931471805599453f);
#endif
}

// rounded pack (epilogue only): +0x8000 round-half-up, then one v_perm_b32
static __device__ __forceinline__ unsigned int pkbf(float lo, float hi) {
  unsigned int ulo = __builtin_bit_cast(unsigned int, lo) + 0x8000u;
  unsigned int uhi = __builtin_bit_cast(unsigned int, hi) + 0x8000u;
  return __builtin_amdgcn_perm(uhi, ulo, 0x07060302u);
}
// truncating pack (P values): single v_perm_b32. Truncation bias cancels in
// O/lsum since lsum is computed from the SAME packed values (ones-MFMA).
static __device__ __forceinline__ unsigned int pkbf_t(float lo, float hi) {
  return __builtin_amdgcn_perm(__builtin_bit_cast(unsigned int, hi),
                               __builtin_bit_cast(unsigned int, lo), 0x07060302u);
}

// ---------------- prep: cast x->bf16, im2col A[4096][1024], weight transposes
// blocks 0..255: xi[b,h,w,ci] = x[b, (w&15)*256+ci, h*4+(w>>4)]
// blocks 256..383: 64x64 LDS-tiled transpose+cast dst[N][K] = src[K][N]
__global__ __launch_bounds__(256) void k_prep(const float* __restrict__ x,
                                              unsigned short* __restrict__ xbf,
                                              unsigned short* __restrict__ A,
                                              const float* __restrict__ Wq, const float* __restrict__ Wconv,
                                              const float* __restrict__ Wkv, const float* __restrict__ Wproj,
                                              unsigned short* __restrict__ WqT, unsigned short* __restrict__ WconvT,
                                              unsigned short* __restrict__ WkvT, unsigned short* __restrict__ WprojT) {
  __shared__ unsigned short tile[64][258];         // 33 KB; aliased as f32 [64][65]
  int blk = blockIdx.x;
  int t = threadIdx.x;
  if (blk >= 256) {                                // weight transpose tiles
    int ti = blk - 256;                            // 128 tiles of 64x64
    const float* src; unsigned short* dst; int K, N, tk, tn;
    if (ti < 16)      { src = Wq;    dst = WqT;    K = 256;  N = 256; tk = ti >> 2;        tn = ti & 3; }
    else if (ti < 80) { src = Wconv; dst = WconvT; K = 1024; N = 256; int j = ti - 16;  tk = j >> 2; tn = j & 3; }
    else if (ti <112) { src = Wkv;   dst = WkvT;   K = 256;  N = 512; int j = ti - 80;  tk = j >> 3; tn = j & 7; }
    else              { src = Wproj; dst = WprojT; K = 256;  N = 256; int j = ti - 112; tk = j >> 2; tn = j & 3; }
    int k0 = tk << 6, n0 = tn << 6;
    float* ft = (float*)&tile[0][0];               // [64][65] f32
    {
      int row = t >> 2, c4 = (t & 3) << 4;         // coalesced src reads
      const float* sp = src + (size_t)(k0 + row) * N + n0 + c4;
#pragma unroll
      for (int j = 0; j < 4; ++j)
        *(f32x4*)&ft[row * 65 + c4 + j * 4] = *(const f32x4*)(sp + j * 4);
    }
    __syncthreads();
    {
      int n = t >> 2, k4 = (t & 3) << 4;           // coalesced dst writes
      unsigned short* dp = dst + (size_t)(n0 + n) * K + k0 + k4;
#pragma unroll
      for (int j = 0; j < 16; j += 4) {
        short4v o;
        o[0] = (short)f2bfu(ft[(k4 + j + 0) * 65 + n]);
        o[1] = (short)f2bfu(ft[(k4 + j + 1) * 65 + n]);
        o[2] = (short)f2bfu(ft[(k4 + j + 2) * 65 + n]);
        o[3] = (short)f2bfu(ft[(k4 + j + 3) * 65 + n]);
        *(short4v*)(dp + j) = o;
      }
    }
    return;
  }
  int b    = blk >> 6;
  int wlow = (blk >> 2) & 15;
  int cib  = blk & 3;
  int ci0  = cib << 6;
  {
    int i = t >> 2, c0 = (t & 3) << 6;
    size_t row = (size_t)(b * 4096 + wlow * 256 + ci0 + i);
    const float* xr = x + row * 256 + c0;
    unsigned short* xw = xbf + row * 256 + c0;
#pragma unroll
    for (int j = 0; j < 16; ++j) {
      f32x4 v = *(const f32x4*)(xr + j * 4);
      short4v ov;
      ov[0] = (short)f2bfu(v[0]); ov[1] = (short)f2bfu(v[1]);
      ov[2] = (short)f2bfu(v[2]); ov[3] = (short)f2bfu(v[3]);
      tile[i][c0 + j*4 + 0] = (unsigned short)ov[0];
      tile[i][c0 + j*4 + 1] = (unsigned short)ov[1];
      tile[i][c0 + j*4 + 2] = (unsigned short)ov[2];
      tile[i][c0 + j*4 + 3] = (unsigned short)ov[3];
      *(short4v*)(xw + j * 4) = ov;
    }
  }
  __syncthreads();
  int wv = t >> 6, lane = t & 63;
#pragma unroll 4
  for (int rep = 0; rep < 64; ++rep) {
    int c = rep * 4 + wv;
    int h = c >> 2;
    int w = ((c & 3) << 4) + wlow;
    int row = b * 1024 + (h >> 1) * 32 + (w >> 1);
    int col = ((h & 1) << 9) + ((w & 1) << 8) + ci0 + lane;
    A[(size_t)row * 1024 + col] = tile[lane][c];
  }
}

// ---------------- fused Q GEMM + conv GEMM (independent, one dispatch) ------
// bid<512: Q = (xbf @ WqT^T + bq)*c1 -> qbf       [16384x256], K=256
// bid>=512: conv partial z=(bid-512)>>7 (z in {0,1}) -> convf + z*1048576,
//           K-half [z*512, z*512+512), bias only in z=0
__global__ __launch_bounds__(256) void k_gemmqc(const unsigned short* __restrict__ xbf,
                                                const unsigned short* __restrict__ WqT,
                                                const float* __restrict__ bq,
                                                unsigned short* __restrict__ qbf,
                                                const unsigned short* __restrict__ Ac,
                                                const unsigned short* __restrict__ WcT,
                                                const float* __restrict__ bc,
                                                float* __restrict__ convf,
                                                float c1) {
  __shared__ __attribute__((aligned(16))) unsigned short As[64 * 32];
  __shared__ __attribute__((aligned(16))) unsigned short Bs[128 * 32];
  int bid = blockIdx.x, t = threadIdx.x;
  int wave = t >> 6, lane = t & 63;
  const unsigned short *A, *Bt; const float* bias;
  int K, m0, n0, kbeg, kend, z; bool isQ;
  if (bid < 512) {
    isQ = true; z = 0;
    A = xbf; Bt = WqT; bias = bq; K = 256;
    m0 = (bid >> 1) << 6; n0 = (bid & 1) << 7; kbeg = 0; kend = 256;
  } else {
    isQ = false;
    int j = bid - 512; z = j >> 7; int r = j & 127;
    A = Ac; Bt = WcT; bias = bc; K = 1024;
    m0 = (r >> 1) << 6; n0 = (r & 1) << 7; kbeg = z << 9; kend = kbeg + 512;
  }
  int lr = lane & 15, lk = (lane >> 4) << 3;
  f32x4 acc[4][2] = {};
  for (int k0 = kbeg; k0 < kend; k0 += 32) {
    __syncthreads();
    {                                              // A tile: 256 chunks of 16B
      int row = t >> 2, kc = (t & 3) << 3;
      __builtin_amdgcn_global_load_lds((const AS1 unsigned int*)(A + (size_t)(m0 + row) * K + k0 + kc),
                                       (AS3 unsigned int*)(As + t * 8), 16, 0, 0);
    }
#pragma unroll
    for (int it = 0; it < 2; ++it) {               // B tile: 512 chunks of 16B
      int c = it * 256 + t;
      int row = c >> 2, kc = (c & 3) << 3;
      __builtin_amdgcn_global_load_lds((const AS1 unsigned int*)(Bt + (size_t)(n0 + row) * K + k0 + kc),
                                       (AS3 unsigned int*)(Bs + c * 8), 16, 0, 0);
    }
    __syncthreads();
    short8 af[4], bfr[2];
#pragma unroll
    for (int mi = 0; mi < 4; ++mi) af[mi]  = *(const short8*)(As + (mi*16 + lr)*32 + lk);
#pragma unroll
    for (int ni = 0; ni < 2; ++ni) bfr[ni] = *(const short8*)(Bs + (wave*32 + ni*16 + lr)*32 + lk);
#pragma unroll
    for (int mi = 0; mi < 4; ++mi)
#pragma unroll
      for (int ni = 0; ni < 2; ++ni)
        acc[mi][ni] = __builtin_amdgcn_mfma_f32_16x16x32_bf16(af[mi], bfr[ni], acc[mi][ni], 0, 0, 0);
  }
  int lrow = (lane >> 4) << 2, lcol = lane & 15;
#pragma unroll
  for (int mi = 0; mi < 4; ++mi) {
#pragma unroll
    for (int ni = 0; ni < 2; ++ni) {
      int gm = m0 + mi*16 + lrow;
      int gn = n0 + wave*32 + ni*16 + lcol;
      float bv = (z == 0) ? bias[gn] : 0.f;
#pragma unroll
      for (int r = 0; r < 4; ++r) {
        float v = acc[mi][ni][r] + bv;
        if (isQ) qbf[(size_t)(gm + r) * 256 + gn] = f2bfu(v * c1);
        else     convf[(size_t)z * 1048576 + (size_t)(gm + r) * 256 + gn] = v;
      }
    }
  }
}

// ---------------- GEMM: C[M][N] = A[M][K] @ Bt[N][K]^T + bias ----------------
// Tile 64x128, 4 waves (each 64x32), BK=32.
// mode 1: f32 -> Cf[M][N]; mode 2 (KV): frag-major KF (gn<256) / VF (gn>=256)
__global__ __launch_bounds__(256) void k_gemm(const unsigned short* __restrict__ A,
                                              const unsigned short* __restrict__ Bt,
                                              const float* __restrict__ bias,
                                              unsigned short* __restrict__ Cb,
                                              float* __restrict__ Cf,
                                              unsigned short* __restrict__ VFout,
                                              int M, int N, int K, int mode, float oscale) {
  __shared__ __attribute__((aligned(16))) unsigned short As[64 * 32];
  __shared__ __attribute__((aligned(16))) unsigned short Bs[128 * 32];
  int t = threadIdx.x;
  int wave = t >> 6, lane = t & 63;
  int m0 = blockIdx.x << 6, n0 = blockIdx.y << 7;
  int lr = lane & 15, lk = (lane >> 4) << 3;
  f32x4 acc[4][2] = {};
  for (int k0 = 0; k0 < K; k0 += 32) {
    __syncthreads();
    {                                              // A tile: 256 chunks of 16B
      int row = t >> 2, kc = (t & 3) << 3;
      __builtin_amdgcn_global_load_lds((const AS1 unsigned int*)(A + (size_t)(m0 + row) * K + k0 + kc),
                                       (AS3 unsigned int*)(As + t * 8), 16, 0, 0);
    }
#pragma unroll
    for (int it = 0; it < 2; ++it) {               // B tile: 512 chunks of 16B
      int c = it * 256 + t;
      int row = c >> 2, kc = (c & 3) << 3;
      __builtin_amdgcn_global_load_lds((const AS1 unsigned int*)(Bt + (size_t)(n0 + row) * K + k0 + kc),
                                       (AS3 unsigned int*)(Bs + c * 8), 16, 0, 0);
    }
    __syncthreads();
    short8 af[4], bfr[2];
#pragma unroll
    for (int mi = 0; mi < 4; ++mi) af[mi]  = *(const short8*)(As + (mi*16 + lr)*32 + lk);
#pragma unroll
    for (int ni = 0; ni < 2; ++ni) bfr[ni] = *(const short8*)(Bs + (wave*32 + ni*16 + lr)*32 + lk);
#pragma unroll
    for (int mi = 0; mi < 4; ++mi)
#pragma unroll
      for (int ni = 0; ni < 2; ++ni)
        acc[mi][ni] = __builtin_amdgcn_mfma_f32_16x16x32_bf16(af[mi], bfr[ni], acc[mi][ni], 0, 0, 0);
  }
  int lrow = (lane >> 4) << 2, lcol = lane & 15;
#pragma unroll
  for (int mi = 0; mi < 4; ++mi) {
#pragma unroll
    for (int ni = 0; ni < 2; ++ni) {
      int gm = m0 + mi*16 + lrow;
      int gn = n0 + wave*32 + ni*16 + lcol;
      float bv = bias[gn];
#pragma unroll
      for (int r = 0; r < 4; ++r) {
        float v = acc[mi][ni][r] + bv;
        if (mode == 1) Cf[(size_t)(gm + r) * N + gn] = v;
        else {
          int tok = gm + r;
          int bb = tok >> 10, k10 = tok & 1023;
          int chunk = k10 >> 5, kc2 = k10 & 31;
          if (gn < 256) {
            int hh = gn >> 5, dd = gn & 31;
            int fr = dd >> 4, hi2 = (dd >> 3) & 1, j = dd & 7;
            size_t base = (((size_t)(bb * 8 + hh) * 32 + chunk) * 2 + fr) * 512;
            Cb[base + (hi2 * 32 + kc2) * 8 + j] = f2bfu(v);        // KF
          } else {
            int hh = (gn - 256) >> 5, dd = (gn - 256) & 31;
            int pos = (kc2 & 16) | (((kc2 >> 2) & 1) << 3) | (((kc2 >> 3) & 1) << 2) | (kc2 & 3);
            int fr = pos >> 4, hi2 = (pos >> 3) & 1, tt = pos & 7;
            size_t base = (((size_t)(bb * 8 + hh) * 32 + chunk) * 2 + fr) * 512;
            VFout[base + (hi2 * 32 + dd) * 8 + tt] = f2bfu(v);     // VF
          }
        }
      }
    }
  }
}

// ---------------- LayerNorm over last dim (256): sums 2 split-K partials ----
__global__ __launch_bounds__(256) void k_ln(const float* __restrict__ conv,
                                            const float* __restrict__ gamma,
                                            const float* __restrict__ beta,
                                            unsigned short* __restrict__ out) {
  int row = (blockIdx.x << 2) + (threadIdx.x >> 6);
  int lane = threadIdx.x & 63;
  const float* r0 = conv + (size_t)row * 256 + lane * 4;
  f32x4 v = *(const f32x4*)r0;
  v += *(const f32x4*)(r0 + 1048576);
  float s = v[0] + v[1] + v[2] + v[3];
#pragma unroll
  for (int m = 1; m < 64; m <<= 1) s += __shfl_xor(s, m);
  float mu = s * (1.f / 256.f);
  f32x4 d; float qv = 0.f;
#pragma unroll
  for (int j = 0; j < 4; ++j) { d[j] = v[j] - mu; qv += d[j] * d[j]; }
#pragma unroll
  for (int m = 1; m < 64; m <<= 1) qv += __shfl_xor(qv, m);
  float rstd = rsqrtf(qv * (1.f / 256.f) + 1e-6f);
  f32x4 g  = *(const f32x4*)(gamma + lane * 4);
  f32x4 bb = *(const f32x4*)(beta  + lane * 4);
  short4v ov;
#pragma unroll
  for (int j = 0; j < 4; ++j) ov[j] = (short)f2bfu(d[j] * rstd * g[j] + bb[j]);
  *(short4v*)(out + (size_t)row * 256 + lane * 4) = ov;
}

// ---------------- flash attention: 2-stage score pipeline -------------------
// (unchanged from round 14 — passing version)
__global__ __launch_bounds__(256) void k_attn(const unsigned short* __restrict__ qb,
                                              const unsigned short* __restrict__ KF,
                                              const unsigned short* __restrict__ VF,
                                              unsigned short* __restrict__ o) {
  __shared__ float comb[2][64][34];                // [qs][lane][32 acc + 2 lsum]
  int flat = blockIdx.y * 32 + blockIdx.x;
  int bh = (flat & 7) * 4 + (flat >> 8);           // XCD-local: fixed flat&7 per bh
  int qg = (flat >> 3) & 31;
  int b = bh >> 3, h = bh & 7;
  int wave = threadIdx.x >> 6, lane = threadIdx.x & 63;
  int qs = wave & 1, kvh = wave >> 1;
  int q0 = (qg * 2 + qs) * 64;
  int lq = lane & 31, hi = lane >> 5;
  const unsigned short* qrA = qb + (size_t)(b * 4096 + q0 + lq) * 256 + h * 32 + hi * 8;
  short8 QA0 = *(const short8*)(qrA);
  short8 QA1 = *(const short8*)(qrA + 16);
  short8 QB0 = *(const short8*)(qrA + 32 * 256);
  short8 QB1 = *(const short8*)(qrA + 32 * 256 + 16);
  const unsigned short* kf = KF + (size_t)bh * 32768 + (size_t)kvh * 16384 + lane * 8;
  const unsigned short* vf = VF + (size_t)bh * 32768 + (size_t)kvh * 16384 + lane * 8;
  const short sone = (short)0x3F80;                // bf16 1.0
  short8 ones = {sone, sone, sone, sone, sone, sone, sone, sone};
  f32x16 accA = {}, accB = {}, alsA = {}, alsB = {};
  f32x16 z = {};
  short8 Ka0 = *(const short8*)(kf), Ka1 = *(const short8*)(kf + 512);
  f32x16 sA = __builtin_amdgcn_mfma_f32_32x32x16_bf16(Ka0, QA0, z, 0, 0, 0);
  sA = __builtin_amdgcn_mfma_f32_32x32x16_bf16(Ka1, QA1, sA, 0, 0, 0);
  f32x16 sB = __builtin_amdgcn_mfma_f32_32x32x16_bf16(Ka0, QB0, z, 0, 0, 0);
  sB = __builtin_amdgcn_mfma_f32_32x32x16_bf16(Ka1, QB1, sB, 0, 0, 0);
  short8 Kc0 = *(const short8*)(kf + 1024), Kc1 = *(const short8*)(kf + 1536);
  short8 Vc0 = *(const short8*)(vf),        Vc1 = *(const short8*)(vf + 512);
  for (int c = 0; c < 15; ++c) {
    int kno = (c == 14) ? 0 : (c + 2) * 1024;
    int vno = (c + 1) * 1024;
    short8 Kn0 = *(const short8*)(kf + kno), Kn1 = *(const short8*)(kf + kno + 512);
    short8 Vn0 = *(const short8*)(vf + vno), Vn1 = *(const short8*)(vf + vno + 512);
    __builtin_amdgcn_s_setprio(1);                 // QK for chunk c+1 FIRST
    f32x16 sAn = __builtin_amdgcn_mfma_f32_32x32x16_bf16(Kc0, QA0, z, 0, 0, 0);
    sAn = __builtin_amdgcn_mfma_f32_32x32x16_bf16(Kc1, QA1, sAn, 0, 0, 0);
    f32x16 sBn = __builtin_amdgcn_mfma_f32_32x32x16_bf16(Kc0, QB0, z, 0, 0, 0);
    sBn = __builtin_amdgcn_mfma_f32_32x32x16_bf16(Kc1, QB1, sBn, 0, 0, 0);
    __builtin_amdgcn_s_setprio(0);
    __builtin_amdgcn_sched_barrier(0);             // pin: QK-next before exp-cur
    union { unsigned int u[4]; short8 s8; } fA0, fA1, fB0, fB1;
#pragma unroll
    for (int w = 0; w < 4; ++w) {
      fA0.u[w] = pkbf_t(fast_exp2(sA[2*w]),     fast_exp2(sA[2*w + 1]));
      fA1.u[w] = pkbf_t(fast_exp2(sA[8 + 2*w]), fast_exp2(sA[9 + 2*w]));
      fB0.u[w] = pkbf_t(fast_exp2(sB[2*w]),     fast_exp2(sB[2*w + 1]));
      fB1.u[w] = pkbf_t(fast_exp2(sB[8 + 2*w]), fast_exp2(sB[9 + 2*w]));
    }
    __builtin_amdgcn_s_setprio(1);
    accA = __builtin_amdgcn_mfma_f32_32x32x16_bf16(Vc0, fA0.s8, accA, 0, 0, 0);
    accA = __builtin_amdgcn_mfma_f32_32x32x16_bf16(Vc1, fA1.s8, accA, 0, 0, 0);
    accB = __builtin_amdgcn_mfma_f32_32x32x16_bf16(Vc0, fB0.s8, accB, 0, 0, 0);
    accB = __builtin_amdgcn_mfma_f32_32x32x16_bf16(Vc1, fB1.s8, accB, 0, 0, 0);
    alsA = __builtin_amdgcn_mfma_f32_32x32x16_bf16(ones, fA0.s8, alsA, 0, 0, 0);
    alsA = __builtin_amdgcn_mfma_f32_32x32x16_bf16(ones, fA1.s8, alsA, 0, 0, 0);
    alsB = __builtin_amdgcn_mfma_f32_32x32x16_bf16(ones, fB0.s8, alsB, 0, 0, 0);
    alsB = __builtin_amdgcn_mfma_f32_32x32x16_bf16(ones, fB1.s8, alsB, 0, 0, 0);
    __builtin_amdgcn_s_setprio(0);
    sA = sAn; sB = sBn;
    Kc0 = Kn0; Kc1 = Kn1; Vc0 = Vn0; Vc1 = Vn1;
  }
  {                                                // epilogue: chunk 15
    union { unsigned int u[4]; short8 s8; } fA0, fA1, fB0, fB1;
#pragma unroll
    for (int w = 0; w < 4; ++w) {
      fA0.u[w] = pkbf_t(fast_exp2(sA[2*w]),     fast_exp2(sA[2*w + 1]));
      fA1.u[w] = pkbf_t(fast_exp2(sA[8 + 2*w]), fast_exp2(sA[9 + 2*w]));
      fB0.u[w] = pkbf_t(fast_exp2(sB[2*w]),     fast_exp2(sB[2*w + 1]));
      fB1.u[w] = pkbf_t(fast_exp2(sB[8 + 2*w]), fast_exp2(sB[9 + 2*w]));
    }
    accA = __builtin_amdgcn_mfma_f32_32x32x16_bf16(Vc0, fA0.s8, accA, 0, 0, 0);
    accA = __builtin_amdgcn_mfma_f32_32x32x16_bf16(Vc1, fA1.s8, accA, 0, 0, 0);
    accB = __builtin_amdgcn_mfma_f32_32x32x16_bf16(Vc0, fB0.s8, accB, 0, 0, 0);
    accB = __builtin_amdgcn_mfma_f32_32x32x16_bf16(Vc1, fB1.s8, accB, 0, 0, 0);
    alsA = __builtin_amdgcn_mfma_f32_32x32x16_bf16(ones, fA0.s8, alsA, 0, 0, 0);
    alsA = __builtin_amdgcn_mfma_f32_32x32x16_bf16(ones, fA1.s8, alsA, 0, 0, 0);
    alsB = __builtin_amdgcn_mfma_f32_32x32x16_bf16(ones, fB0.s8, alsB, 0, 0, 0);
    alsB = __builtin_amdgcn_mfma_f32_32x32x16_bf16(ones, fB1.s8, alsB, 0, 0, 0);
  }
  float lsA = alsA[0], lsB = alsB[0];              // full wave-kv sum (all rows equal)
  if (kvh) {                                       // upper half: publish partials
    float* dst = &comb[qs][lane][0];
#pragma unroll
    for (int r = 0; r < 16; r += 2) {
      *(f32x2*)&dst[r]      = (f32x2){accA[r], accA[r+1]};
      *(f32x2*)&dst[16 + r] = (f32x2){accB[r], accB[r+1]};
    }
    *(f32x2*)&dst[32] = (f32x2){lsA, lsB};
  }
  __syncthreads();
  if (!kvh) {                                      // lower half: combine + store
    const float* src = &comb[qs][lane][0];
#pragma unroll
    for (int r = 0; r < 16; ++r) { accA[r] += src[r]; accB[r] += src[16 + r]; }
    lsA += src[32]; lsB += src[33];                // lsum already full per half
    float invA = 1.f / lsA, invB = 1.f / lsB;
    unsigned short* orA = o + (size_t)(b * 4096 + q0 + lq) * 256 + h * 32 + 4 * hi;
    unsigned short* orB = orA + (size_t)32 * 256;
#pragma unroll
    for (int g = 0; g < 4; ++g) {
      u32x2 ovA, ovB;
      ovA[0] = pkbf(accA[4*g+0] * invA, accA[4*g+1] * invA);
      ovA[1] = pkbf(accA[4*g+2] * invA, accA[4*g+3] * invA);
      ovB[0] = pkbf(accB[4*g+0] * invB, accB[4*g+1] * invB);
      ovB[1] = pkbf(accB[4*g+2] * invB, accB[4*g+3] * invB);
      *(u32x2*)(orA + 8 * g) = ovA;
      *(u32x2*)(orB + 8 * g) = ovB;
    }
  }
}

// ---------------------------------------------------------------------------
extern "C" void kernel_launch(void* const* d_in, const int* in_sizes, int n_in,
                              void* d_out, int out_size, void* d_ws, size_t ws_size,
                              hipStream_t stream) {
  const float* x     = (const float*)d_in[0];
  const float* Wq    = (const float*)d_in[1];
  const float* bq    = (const float*)d_in[2];
  const float* Wconv = (const float*)d_in[3];
  const float* bconv = (const float*)d_in[4];
  const float* ln_s  = (const float*)d_in[5];
  const float* ln_b  = (const float*)d_in[6];
  const float* Wkv   = (const float*)d_in[7];
  const float* bkv   = (const float*)d_in[8];
  const float* Wproj = (const float*)d_in[9];
  const float* bproj = (const float*)d_in[10];

  char* ws = (char*)d_ws;
  unsigned short* x_bf   = (unsigned short*)(ws);                       // 8 MiB (dead after Q GEMM)
  unsigned short* VF     = (unsigned short*)(ws);                       // 2 MiB, written by KV GEMM
  unsigned short* q_bf   = (unsigned short*)(ws + (size_t)(8  << 20));  // 8 MiB
  unsigned short* Aconv  = (unsigned short*)(ws + (size_t)(16 << 20));  // 8 MiB
  unsigned short* attn_o = Aconv;            // reuse: conv GEMM done before attn
  float*          conv_f = (float*)(ws + (size_t)(24 << 20));           // 8 MiB (2 partials)
  unsigned short* norm_b = (unsigned short*)(ws + (size_t)(40 << 20));  // 2 MiB
  unsigned short* KF     = (unsigned short*)(ws + (size_t)(42 << 20));  // 2 MiB
  unsigned short* WqT    = (unsigned short*)(ws + (size_t)(44 << 20));
  unsigned short* WconvT = WqT + 65536;
  unsigned short* WkvT   = WconvT + 262144;
  unsigned short* WprojT = WkvT + 131072;

  const float c1 = (float)(0.17677669529663687 * 1.4426950408889634); // scale*log2e

  k_prep<<<384, 256, 0, stream>>>(x, x_bf, Aconv, Wq, Wconv, Wkv, Wproj,
                                  WqT, WconvT, WkvT, WprojT);
  // fused: Q GEMM (512 blocks) + conv GEMM split-K x2 (256 blocks)
  k_gemmqc<<<768, 256, 0, stream>>>(x_bf, WqT, bq, q_bf,
                                    Aconv, WconvT, bconv, conv_f, c1);
  k_ln<<<1024, 256, 0, stream>>>(conv_f, ln_s, ln_b, norm_b);
  // kv = norm @ Wkv + bkv               [4096 x 512], K=256; -> KF + VF (frag-major)
  k_gemm<<<dim3(64, 4), 256, 0, stream>>>(norm_b, WkvT, bkv, KF, nullptr, VF, 4096, 512, 256, 2, 1.f);
  k_attn<<<dim3(32, 32), 256, 0, stream>>>(q_bf, KF, VF, attn_o);
  // out = attn @ Wproj + bproj          [16384 x 256], K=256  (fp32 out)
  k_gemm<<<dim3(256, 2), 256, 0, stream>>>(attn_o, WprojT, bproj, nullptr, (float*)d_out, nullptr, 16384, 256, 256, 1, 1.f);
}

// Round 16
// 81.814 us; speedup vs baseline: 1.0165x; 1.0165x over previous
//
#include <hip/hip_runtime.h>
#include <hip/hip_bf16.h>
#include <stdint.h>

// ---------------------------------------------------------------------------
// EfficientSelfAttention (PVT SRA): B=4, N=4096, C=256, HEADS=8, hd=32, SR=2
// Pipeline: prep (cast x + im2col + LDS-tiled weight transpose) |
//           GEMM(Q)+GEMM(conv,split-K x4) fused | LN(sum partials) |
//           GEMM(KV -> frag-major K,V) |
//           flash-attn (frag streams, kv-split x2, ones-MFMA lsum,
//                       2-stage score pipeline: QK(c+1) issued before exp(c)) |
//           GEMM(proj)
// (Round-14 configuration — best measured: 82.1 us.)
// ---------------------------------------------------------------------------

typedef __attribute__((ext_vector_type(8))) short short8;
typedef __attribute__((ext_vector_type(4))) short short4v;
typedef __attribute__((ext_vector_type(2))) float f32x2;
typedef __attribute__((ext_vector_type(2))) unsigned int u32x2;
typedef __attribute__((ext_vector_type(4))) float f32x4;
typedef __attribute__((ext_vector_type(16))) float f32x16;

#define AS1 __attribute__((address_space(1)))
#define AS3 __attribute__((address_space(3)))

static __device__ __forceinline__ unsigned short f2bfu(float f) {
  __hip_bfloat16 h = __float2bfloat16(f);
  unsigned short u; __builtin_memcpy(&u, &h, 2); return u;
}

static __device__ __forceinline__ float fast_exp2(float x) {
#if __has_builtin(__builtin_amdgcn_exp2f)
  return __builtin_amdgcn_exp2f(x);
#else
  return __expf(x * 0.6931471805599453f);
#endif
}

// rounded pack (epilogue only): +0x8000 round-half-up, then one v_perm_b32
static __device__ __forceinline__ unsigned int pkbf(float lo, float hi) {
  unsigned int ulo = __builtin_bit_cast(unsigned int, lo) + 0x8000u;
  unsigned int uhi = __builtin_bit_cast(unsigned int, hi) + 0x8000u;
  return __builtin_amdgcn_perm(uhi, ulo, 0x07060302u);
}
// truncating pack (P values): single v_perm_b32. Truncation bias cancels in
// O/lsum since lsum is computed from the SAME packed values (ones-MFMA).
static __device__ __forceinline__ unsigned int pkbf_t(float lo, float hi) {
  return __builtin_amdgcn_perm(__builtin_bit_cast(unsigned int, hi),
                               __builtin_bit_cast(unsigned int, lo), 0x07060302u);
}

// ---------------- prep: cast x->bf16, im2col A[4096][1024], weight transposes
// blocks 0..255: xi[b,h,w,ci] = x[b, (w&15)*256+ci, h*4+(w>>4)]
// blocks 256..383: 64x64 LDS-tiled transpose+cast dst[N][K] = src[K][N]
__global__ __launch_bounds__(256) void k_prep(const float* __restrict__ x,
                                              unsigned short* __restrict__ xbf,
                                              unsigned short* __restrict__ A,
                                              const float* __restrict__ Wq, const float* __restrict__ Wconv,
                                              const float* __restrict__ Wkv, const float* __restrict__ Wproj,
                                              unsigned short* __restrict__ WqT, unsigned short* __restrict__ WconvT,
                                              unsigned short* __restrict__ WkvT, unsigned short* __restrict__ WprojT) {
  __shared__ unsigned short tile[64][258];         // 33 KB; aliased as f32 [64][65]
  int blk = blockIdx.x;
  int t = threadIdx.x;
  if (blk >= 256) {                                // weight transpose tiles
    int ti = blk - 256;                            // 128 tiles of 64x64
    const float* src; unsigned short* dst; int K, N, tk, tn;
    if (ti < 16)      { src = Wq;    dst = WqT;    K = 256;  N = 256; tk = ti >> 2;        tn = ti & 3; }
    else if (ti < 80) { src = Wconv; dst = WconvT; K = 1024; N = 256; int j = ti - 16;  tk = j >> 2; tn = j & 3; }
    else if (ti <112) { src = Wkv;   dst = WkvT;   K = 256;  N = 512; int j = ti - 80;  tk = j >> 3; tn = j & 7; }
    else              { src = Wproj; dst = WprojT; K = 256;  N = 256; int j = ti - 112; tk = j >> 2; tn = j & 3; }
    int k0 = tk << 6, n0 = tn << 6;
    float* ft = (float*)&tile[0][0];               // [64][65] f32
    {
      int row = t >> 2, c4 = (t & 3) << 4;         // coalesced src reads
      const float* sp = src + (size_t)(k0 + row) * N + n0 + c4;
#pragma unroll
      for (int j = 0; j < 4; ++j)
        *(f32x4*)&ft[row * 65 + c4 + j * 4] = *(const f32x4*)(sp + j * 4);
    }
    __syncthreads();
    {
      int n = t >> 2, k4 = (t & 3) << 4;           // coalesced dst writes
      unsigned short* dp = dst + (size_t)(n0 + n) * K + k0 + k4;
#pragma unroll
      for (int j = 0; j < 16; j += 4) {
        short4v o;
        o[0] = (short)f2bfu(ft[(k4 + j + 0) * 65 + n]);
        o[1] = (short)f2bfu(ft[(k4 + j + 1) * 65 + n]);
        o[2] = (short)f2bfu(ft[(k4 + j + 2) * 65 + n]);
        o[3] = (short)f2bfu(ft[(k4 + j + 3) * 65 + n]);
        *(short4v*)(dp + j) = o;
      }
    }
    return;
  }
  int b    = blk >> 6;
  int wlow = (blk >> 2) & 15;
  int cib  = blk & 3;
  int ci0  = cib << 6;
  {
    int i = t >> 2, c0 = (t & 3) << 6;
    size_t row = (size_t)(b * 4096 + wlow * 256 + ci0 + i);
    const float* xr = x + row * 256 + c0;
    unsigned short* xw = xbf + row * 256 + c0;
#pragma unroll
    for (int j = 0; j < 16; ++j) {
      f32x4 v = *(const f32x4*)(xr + j * 4);
      short4v ov;
      ov[0] = (short)f2bfu(v[0]); ov[1] = (short)f2bfu(v[1]);
      ov[2] = (short)f2bfu(v[2]); ov[3] = (short)f2bfu(v[3]);
      tile[i][c0 + j*4 + 0] = (unsigned short)ov[0];
      tile[i][c0 + j*4 + 1] = (unsigned short)ov[1];
      tile[i][c0 + j*4 + 2] = (unsigned short)ov[2];
      tile[i][c0 + j*4 + 3] = (unsigned short)ov[3];
      *(short4v*)(xw + j * 4) = ov;
    }
  }
  __syncthreads();
  int wv = t >> 6, lane = t & 63;
#pragma unroll 4
  for (int rep = 0; rep < 64; ++rep) {
    int c = rep * 4 + wv;
    int h = c >> 2;
    int w = ((c & 3) << 4) + wlow;
    int row = b * 1024 + (h >> 1) * 32 + (w >> 1);
    int col = ((h & 1) << 9) + ((w & 1) << 8) + ci0 + lane;
    A[(size_t)row * 1024 + col] = tile[lane][c];
  }
}

// ---------------- fused Q GEMM + conv GEMM (independent, one dispatch) ------
// bid<512: Q = (xbf @ WqT^T + bq)*c1 -> qbf       [16384x256], K=256
// bid>=512: conv partial z=(bid-512)>>7 -> convf + z*1048576   [4096x256],
//           K-quarter [z*256, z*256+256), bias only in z=0
__global__ __launch_bounds__(256) void k_gemmqc(const unsigned short* __restrict__ xbf,
                                                const unsigned short* __restrict__ WqT,
                                                const float* __restrict__ bq,
                                                unsigned short* __restrict__ qbf,
                                                const unsigned short* __restrict__ Ac,
                                                const unsigned short* __restrict__ WcT,
                                                const float* __restrict__ bc,
                                                float* __restrict__ convf,
                                                float c1) {
  __shared__ __attribute__((aligned(16))) unsigned short As[64 * 32];
  __shared__ __attribute__((aligned(16))) unsigned short Bs[128 * 32];
  int bid = blockIdx.x, t = threadIdx.x;
  int wave = t >> 6, lane = t & 63;
  const unsigned short *A, *Bt; const float* bias;
  int K, m0, n0, kbeg, z; bool isQ;
  if (bid < 512) {
    isQ = true; z = 0;
    A = xbf; Bt = WqT; bias = bq; K = 256;
    m0 = (bid >> 1) << 6; n0 = (bid & 1) << 7; kbeg = 0;
  } else {
    isQ = false;
    int j = bid - 512; z = j >> 7; int r = j & 127;
    A = Ac; Bt = WcT; bias = bc; K = 1024;
    m0 = (r >> 1) << 6; n0 = (r & 1) << 7; kbeg = z << 8;
  }
  int kend = kbeg + 256;
  int lr = lane & 15, lk = (lane >> 4) << 3;
  f32x4 acc[4][2] = {};
  for (int k0 = kbeg; k0 < kend; k0 += 32) {
    __syncthreads();
    {                                              // A tile: 256 chunks of 16B
      int row = t >> 2, kc = (t & 3) << 3;
      __builtin_amdgcn_global_load_lds((const AS1 unsigned int*)(A + (size_t)(m0 + row) * K + k0 + kc),
                                       (AS3 unsigned int*)(As + t * 8), 16, 0, 0);
    }
#pragma unroll
    for (int it = 0; it < 2; ++it) {               // B tile: 512 chunks of 16B
      int c = it * 256 + t;
      int row = c >> 2, kc = (c & 3) << 3;
      __builtin_amdgcn_global_load_lds((const AS1 unsigned int*)(Bt + (size_t)(n0 + row) * K + k0 + kc),
                                       (AS3 unsigned int*)(Bs + c * 8), 16, 0, 0);
    }
    __syncthreads();
    short8 af[4], bfr[2];
#pragma unroll
    for (int mi = 0; mi < 4; ++mi) af[mi]  = *(const short8*)(As + (mi*16 + lr)*32 + lk);
#pragma unroll
    for (int ni = 0; ni < 2; ++ni) bfr[ni] = *(const short8*)(Bs + (wave*32 + ni*16 + lr)*32 + lk);
#pragma unroll
    for (int mi = 0; mi < 4; ++mi)
#pragma unroll
      for (int ni = 0; ni < 2; ++ni)
        acc[mi][ni] = __builtin_amdgcn_mfma_f32_16x16x32_bf16(af[mi], bfr[ni], acc[mi][ni], 0, 0, 0);
  }
  int lrow = (lane >> 4) << 2, lcol = lane & 15;
#pragma unroll
  for (int mi = 0; mi < 4; ++mi) {
#pragma unroll
    for (int ni = 0; ni < 2; ++ni) {
      int gm = m0 + mi*16 + lrow;
      int gn = n0 + wave*32 + ni*16 + lcol;
      float bv = (z == 0) ? bias[gn] : 0.f;
#pragma unroll
      for (int r = 0; r < 4; ++r) {
        float v = acc[mi][ni][r] + bv;
        if (isQ) qbf[(size_t)(gm + r) * 256 + gn] = f2bfu(v * c1);
        else     convf[(size_t)z * 1048576 + (size_t)(gm + r) * 256 + gn] = v;
      }
    }
  }
}

// ---------------- GEMM: C[M][N] = A[M][K] @ Bt[N][K]^T + bias ----------------
// Tile 64x128, 4 waves (each 64x32), BK=32.
// mode 1: f32 -> Cf[M][N]; mode 2 (KV): frag-major KF (gn<256) / VF (gn>=256)
__global__ __launch_bounds__(256) void k_gemm(const unsigned short* __restrict__ A,
                                              const unsigned short* __restrict__ Bt,
                                              const float* __restrict__ bias,
                                              unsigned short* __restrict__ Cb,
                                              float* __restrict__ Cf,
                                              unsigned short* __restrict__ VFout,
                                              int M, int N, int K, int mode, float oscale) {
  __shared__ __attribute__((aligned(16))) unsigned short As[64 * 32];
  __shared__ __attribute__((aligned(16))) unsigned short Bs[128 * 32];
  int t = threadIdx.x;
  int wave = t >> 6, lane = t & 63;
  int m0 = blockIdx.x << 6, n0 = blockIdx.y << 7;
  int lr = lane & 15, lk = (lane >> 4) << 3;
  f32x4 acc[4][2] = {};
  for (int k0 = 0; k0 < K; k0 += 32) {
    __syncthreads();
    {                                              // A tile: 256 chunks of 16B
      int row = t >> 2, kc = (t & 3) << 3;
      __builtin_amdgcn_global_load_lds((const AS1 unsigned int*)(A + (size_t)(m0 + row) * K + k0 + kc),
                                       (AS3 unsigned int*)(As + t * 8), 16, 0, 0);
    }
#pragma unroll
    for (int it = 0; it < 2; ++it) {               // B tile: 512 chunks of 16B
      int c = it * 256 + t;
      int row = c >> 2, kc = (c & 3) << 3;
      __builtin_amdgcn_global_load_lds((const AS1 unsigned int*)(Bt + (size_t)(n0 + row) * K + k0 + kc),
                                       (AS3 unsigned int*)(Bs + c * 8), 16, 0, 0);
    }
    __syncthreads();
    short8 af[4], bfr[2];
#pragma unroll
    for (int mi = 0; mi < 4; ++mi) af[mi]  = *(const short8*)(As + (mi*16 + lr)*32 + lk);
#pragma unroll
    for (int ni = 0; ni < 2; ++ni) bfr[ni] = *(const short8*)(Bs + (wave*32 + ni*16 + lr)*32 + lk);
#pragma unroll
    for (int mi = 0; mi < 4; ++mi)
#pragma unroll
      for (int ni = 0; ni < 2; ++ni)
        acc[mi][ni] = __builtin_amdgcn_mfma_f32_16x16x32_bf16(af[mi], bfr[ni], acc[mi][ni], 0, 0, 0);
  }
  int lrow = (lane >> 4) << 2, lcol = lane & 15;
#pragma unroll
  for (int mi = 0; mi < 4; ++mi) {
#pragma unroll
    for (int ni = 0; ni < 2; ++ni) {
      int gm = m0 + mi*16 + lrow;
      int gn = n0 + wave*32 + ni*16 + lcol;
      float bv = bias[gn];
#pragma unroll
      for (int r = 0; r < 4; ++r) {
        float v = acc[mi][ni][r] + bv;
        if (mode == 1) Cf[(size_t)(gm + r) * N + gn] = v;
        else {
          int tok = gm + r;
          int bb = tok >> 10, k10 = tok & 1023;
          int chunk = k10 >> 5, kc2 = k10 & 31;
          if (gn < 256) {
            int hh = gn >> 5, dd = gn & 31;
            int fr = dd >> 4, hi2 = (dd >> 3) & 1, j = dd & 7;
            size_t base = (((size_t)(bb * 8 + hh) * 32 + chunk) * 2 + fr) * 512;
            Cb[base + (hi2 * 32 + kc2) * 8 + j] = f2bfu(v);        // KF
          } else {
            int hh = (gn - 256) >> 5, dd = (gn - 256) & 31;
            int pos = (kc2 & 16) | (((kc2 >> 2) & 1) << 3) | (((kc2 >> 3) & 1) << 2) | (kc2 & 3);
            int fr = pos >> 4, hi2 = (pos >> 3) & 1, tt = pos & 7;
            size_t base = (((size_t)(bb * 8 + hh) * 32 + chunk) * 2 + fr) * 512;
            VFout[base + (hi2 * 32 + dd) * 8 + tt] = f2bfu(v);     // VF
          }
        }
      }
    }
  }
}

// ---------------- LayerNorm over last dim (256): sums 4 split-K partials ----
__global__ __launch_bounds__(256) void k_ln(const float* __restrict__ conv,
                                            const float* __restrict__ gamma,
                                            const float* __restrict__ beta,
                                            unsigned short* __restrict__ out) {
  int row = (blockIdx.x << 2) + (threadIdx.x >> 6);
  int lane = threadIdx.x & 63;
  const float* r0 = conv + (size_t)row * 256 + lane * 4;
  f32x4 v = *(const f32x4*)r0;
  v += *(const f32x4*)(r0 + 1048576);
  v += *(const f32x4*)(r0 + 2097152);
  v += *(const f32x4*)(r0 + 3145728);
  float s = v[0] + v[1] + v[2] + v[3];
#pragma unroll
  for (int m = 1; m < 64; m <<= 1) s += __shfl_xor(s, m);
  float mu = s * (1.f / 256.f);
  f32x4 d; float qv = 0.f;
#pragma unroll
  for (int j = 0; j < 4; ++j) { d[j] = v[j] - mu; qv += d[j] * d[j]; }
#pragma unroll
  for (int m = 1; m < 64; m <<= 1) qv += __shfl_xor(qv, m);
  float rstd = rsqrtf(qv * (1.f / 256.f) + 1e-6f);
  f32x4 g  = *(const f32x4*)(gamma + lane * 4);
  f32x4 bb = *(const f32x4*)(beta  + lane * 4);
  short4v ov;
#pragma unroll
  for (int j = 0; j < 4; ++j) ov[j] = (short)f2bfu(d[j] * rstd * g[j] + bb[j]);
  *(short4v*)(out + (size_t)row * 256 + lane * 4) = ov;
}

// ---------------- flash attention: 2-stage score pipeline -------------------
// grid (32,32) flat-remapped, 4 waves = 2 q-subtiles x 2 kv-halves.
// Scores for chunk c+1 (QK MFMAs) are issued BEFORE the exp/pack/PV of
// chunk c (sched_barrier pins order) — QK result latency drains under the
// ~300 VALU cycles of the current chunk instead of stalling the wave.
__global__ __launch_bounds__(256) void k_attn(const unsigned short* __restrict__ qb,
                                              const unsigned short* __restrict__ KF,
                                              const unsigned short* __restrict__ VF,
                                              unsigned short* __restrict__ o) {
  __shared__ float comb[2][64][34];                // [qs][lane][32 acc + 2 lsum]
  int flat = blockIdx.y * 32 + blockIdx.x;
  int bh = (flat & 7) * 4 + (flat >> 8);           // XCD-local: fixed flat&7 per bh
  int qg = (flat >> 3) & 31;
  int b = bh >> 3, h = bh & 7;
  int wave = threadIdx.x >> 6, lane = threadIdx.x & 63;
  int qs = wave & 1, kvh = wave >> 1;
  int q0 = (qg * 2 + qs) * 64;
  int lq = lane & 31, hi = lane >> 5;
  const unsigned short* qrA = qb + (size_t)(b * 4096 + q0 + lq) * 256 + h * 32 + hi * 8;
  short8 QA0 = *(const short8*)(qrA);
  short8 QA1 = *(const short8*)(qrA + 16);
  short8 QB0 = *(const short8*)(qrA + 32 * 256);
  short8 QB1 = *(const short8*)(qrA + 32 * 256 + 16);
  const unsigned short* kf = KF + (size_t)bh * 32768 + (size_t)kvh * 16384 + lane * 8;
  const unsigned short* vf = VF + (size_t)bh * 32768 + (size_t)kvh * 16384 + lane * 8;
  const short sone = (short)0x3F80;                // bf16 1.0
  short8 ones = {sone, sone, sone, sone, sone, sone, sone, sone};
  f32x16 accA = {}, accB = {}, alsA = {}, alsB = {};
  f32x16 z = {};
  // prologue: scores for chunk 0; prefetch K chunk1, V chunk0
  short8 Ka0 = *(const short8*)(kf), Ka1 = *(const short8*)(kf + 512);
  f32x16 sA = __builtin_amdgcn_mfma_f32_32x32x16_bf16(Ka0, QA0, z, 0, 0, 0);
  sA = __builtin_amdgcn_mfma_f32_32x32x16_bf16(Ka1, QA1, sA, 0, 0, 0);
  f32x16 sB = __builtin_amdgcn_mfma_f32_32x32x16_bf16(Ka0, QB0, z, 0, 0, 0);
  sB = __builtin_amdgcn_mfma_f32_32x32x16_bf16(Ka1, QB1, sB, 0, 0, 0);
  short8 Kc0 = *(const short8*)(kf + 1024), Kc1 = *(const short8*)(kf + 1536);
  short8 Vc0 = *(const short8*)(vf),        Vc1 = *(const short8*)(vf + 512);
  for (int c = 0; c < 15; ++c) {
    int kno = (c == 14) ? 0 : (c + 2) * 1024;      // dummy at c=14 (unused)
    int vno = (c + 1) * 1024;
    short8 Kn0 = *(const short8*)(kf + kno), Kn1 = *(const short8*)(kf + kno + 512);
    short8 Vn0 = *(const short8*)(vf + vno), Vn1 = *(const short8*)(vf + vno + 512);
    __builtin_amdgcn_s_setprio(1);                 // QK for chunk c+1 FIRST
    f32x16 sAn = __builtin_amdgcn_mfma_f32_32x32x16_bf16(Kc0, QA0, z, 0, 0, 0);
    sAn = __builtin_amdgcn_mfma_f32_32x32x16_bf16(Kc1, QA1, sAn, 0, 0, 0);
    f32x16 sBn = __builtin_amdgcn_mfma_f32_32x32x16_bf16(Kc0, QB0, z, 0, 0, 0);
    sBn = __builtin_amdgcn_mfma_f32_32x32x16_bf16(Kc1, QB1, sBn, 0, 0, 0);
    __builtin_amdgcn_s_setprio(0);
    __builtin_amdgcn_sched_barrier(0);             // pin: QK-next before exp-cur
    union { unsigned int u[4]; short8 s8; } fA0, fA1, fB0, fB1;
#pragma unroll
    for (int w = 0; w < 4; ++w) {
      fA0.u[w] = pkbf_t(fast_exp2(sA[2*w]),     fast_exp2(sA[2*w + 1]));
      fA1.u[w] = pkbf_t(fast_exp2(sA[8 + 2*w]), fast_exp2(sA[9 + 2*w]));
      fB0.u[w] = pkbf_t(fast_exp2(sB[2*w]),     fast_exp2(sB[2*w + 1]));
      fB1.u[w] = pkbf_t(fast_exp2(sB[8 + 2*w]), fast_exp2(sB[9 + 2*w]));
    }
    __builtin_amdgcn_s_setprio(1);
    accA = __builtin_amdgcn_mfma_f32_32x32x16_bf16(Vc0, fA0.s8, accA, 0, 0, 0);
    accA = __builtin_amdgcn_mfma_f32_32x32x16_bf16(Vc1, fA1.s8, accA, 0, 0, 0);
    accB = __builtin_amdgcn_mfma_f32_32x32x16_bf16(Vc0, fB0.s8, accB, 0, 0, 0);
    accB = __builtin_amdgcn_mfma_f32_32x32x16_bf16(Vc1, fB1.s8, accB, 0, 0, 0);
    alsA = __builtin_amdgcn_mfma_f32_32x32x16_bf16(ones, fA0.s8, alsA, 0, 0, 0);
    alsA = __builtin_amdgcn_mfma_f32_32x32x16_bf16(ones, fA1.s8, alsA, 0, 0, 0);
    alsB = __builtin_amdgcn_mfma_f32_32x32x16_bf16(ones, fB0.s8, alsB, 0, 0, 0);
    alsB = __builtin_amdgcn_mfma_f32_32x32x16_bf16(ones, fB1.s8, alsB, 0, 0, 0);
    __builtin_amdgcn_s_setprio(0);
    sA = sAn; sB = sBn;
    Kc0 = Kn0; Kc1 = Kn1; Vc0 = Vn0; Vc1 = Vn1;
  }
  {                                                // epilogue: chunk 15
    union { unsigned int u[4]; short8 s8; } fA0, fA1, fB0, fB1;
#pragma unroll
    for (int w = 0; w < 4; ++w) {
      fA0.u[w] = pkbf_t(fast_exp2(sA[2*w]),     fast_exp2(sA[2*w + 1]));
      fA1.u[w] = pkbf_t(fast_exp2(sA[8 + 2*w]), fast_exp2(sA[9 + 2*w]));
      fB0.u[w] = pkbf_t(fast_exp2(sB[2*w]),     fast_exp2(sB[2*w + 1]));
      fB1.u[w] = pkbf_t(fast_exp2(sB[8 + 2*w]), fast_exp2(sB[9 + 2*w]));
    }
    accA = __builtin_amdgcn_mfma_f32_32x32x16_bf16(Vc0, fA0.s8, accA, 0, 0, 0);
    accA = __builtin_amdgcn_mfma_f32_32x32x16_bf16(Vc1, fA1.s8, accA, 0, 0, 0);
    accB = __builtin_amdgcn_mfma_f32_32x32x16_bf16(Vc0, fB0.s8, accB, 0, 0, 0);
    accB = __builtin_amdgcn_mfma_f32_32x32x16_bf16(Vc1, fB1.s8, accB, 0, 0, 0);
    alsA = __builtin_amdgcn_mfma_f32_32x32x16_bf16(ones, fA0.s8, alsA, 0, 0, 0);
    alsA = __builtin_amdgcn_mfma_f32_32x32x16_bf16(ones, fA1.s8, alsA, 0, 0, 0);
    alsB = __builtin_amdgcn_mfma_f32_32x32x16_bf16(ones, fB0.s8, alsB, 0, 0, 0);
    alsB = __builtin_amdgcn_mfma_f32_32x32x16_bf16(ones, fB1.s8, alsB, 0, 0, 0);
  }
  float lsA = alsA[0], lsB = alsB[0];              // full wave-kv sum (all rows equal)
  if (kvh) {                                       // upper half: publish partials
    float* dst = &comb[qs][lane][0];
#pragma unroll
    for (int r = 0; r < 16; r += 2) {
      *(f32x2*)&dst[r]      = (f32x2){accA[r], accA[r+1]};
      *(f32x2*)&dst[16 + r] = (f32x2){accB[r], accB[r+1]};
    }
    *(f32x2*)&dst[32] = (f32x2){lsA, lsB};
  }
  __syncthreads();
  if (!kvh) {                                      // lower half: combine + store
    const float* src = &comb[qs][lane][0];
#pragma unroll
    for (int r = 0; r < 16; ++r) { accA[r] += src[r]; accB[r] += src[16 + r]; }
    lsA += src[32]; lsB += src[33];                // lsum already full per half
    float invA = 1.f / lsA, invB = 1.f / lsB;
    unsigned short* orA = o + (size_t)(b * 4096 + q0 + lq) * 256 + h * 32 + 4 * hi;
    unsigned short* orB = orA + (size_t)32 * 256;
#pragma unroll
    for (int g = 0; g < 4; ++g) {
      u32x2 ovA, ovB;
      ovA[0] = pkbf(accA[4*g+0] * invA, accA[4*g+1] * invA);
      ovA[1] = pkbf(accA[4*g+2] * invA, accA[4*g+3] * invA);
      ovB[0] = pkbf(accB[4*g+0] * invB, accB[4*g+1] * invB);
      ovB[1] = pkbf(accB[4*g+2] * invB, accB[4*g+3] * invB);
      *(u32x2*)(orA + 8 * g) = ovA;
      *(u32x2*)(orB + 8 * g) = ovB;
    }
  }
}

// ---------------------------------------------------------------------------
extern "C" void kernel_launch(void* const* d_in, const int* in_sizes, int n_in,
                              void* d_out, int out_size, void* d_ws, size_t ws_size,
                              hipStream_t stream) {
  const float* x     = (const float*)d_in[0];
  const float* Wq    = (const float*)d_in[1];
  const float* bq    = (const float*)d_in[2];
  const float* Wconv = (const float*)d_in[3];
  const float* bconv = (const float*)d_in[4];
  const float* ln_s  = (const float*)d_in[5];
  const float* ln_b  = (const float*)d_in[6];
  const float* Wkv   = (const float*)d_in[7];
  const float* bkv   = (const float*)d_in[8];
  const float* Wproj = (const float*)d_in[9];
  const float* bproj = (const float*)d_in[10];

  char* ws = (char*)d_ws;
  unsigned short* x_bf   = (unsigned short*)(ws);                       // 8 MiB (dead after Q GEMM)
  unsigned short* VF     = (unsigned short*)(ws);                       // 2 MiB, written by KV GEMM
  unsigned short* q_bf   = (unsigned short*)(ws + (size_t)(8  << 20));  // 8 MiB
  unsigned short* Aconv  = (unsigned short*)(ws + (size_t)(16 << 20));  // 8 MiB
  unsigned short* attn_o = Aconv;            // reuse: conv GEMM done before attn
  float*          conv_f = (float*)(ws + (size_t)(24 << 20));           // 16 MiB (4 partials)
  unsigned short* norm_b = (unsigned short*)(ws + (size_t)(40 << 20));  // 2 MiB
  unsigned short* KF     = (unsigned short*)(ws + (size_t)(42 << 20));  // 2 MiB
  unsigned short* WqT    = (unsigned short*)(ws + (size_t)(44 << 20));
  unsigned short* WconvT = WqT + 65536;
  unsigned short* WkvT   = WconvT + 262144;
  unsigned short* WprojT = WkvT + 131072;

  const float c1 = (float)(0.17677669529663687 * 1.4426950408889634); // scale*log2e

  k_prep<<<384, 256, 0, stream>>>(x, x_bf, Aconv, Wq, Wconv, Wkv, Wproj,
                                  WqT, WconvT, WkvT, WprojT);
  // fused: Q GEMM (512 blocks) + conv GEMM split-K x4 (512 blocks)
  k_gemmqc<<<1024, 256, 0, stream>>>(x_bf, WqT, bq, q_bf,
                                     Aconv, WconvT, bconv, conv_f, c1);
  k_ln<<<1024, 256, 0, stream>>>(conv_f, ln_s, ln_b, norm_b);
  // kv = norm @ Wkv + bkv               [4096 x 512], K=256; -> KF + VF (frag-major)
  k_gemm<<<dim3(64, 4), 256, 0, stream>>>(norm_b, WkvT, bkv, KF, nullptr, VF, 4096, 512, 256, 2, 1.f);
  k_attn<<<dim3(32, 32), 256, 0, stream>>>(q_bf, KF, VF, attn_o);
  // out = attn @ Wproj + bproj          [16384 x 256], K=256  (fp32 out)
  k_gemm<<<dim3(256, 2), 256, 0, stream>>>(attn_o, WprojT, bproj, nullptr, (float*)d_out, nullptr, 16384, 256, 256, 1, 1.f);
}